// Round 12
// baseline (224.410 us; speedup 1.0000x reference)
//
#include <hip/hip_runtime.h>
#include <cstdint>

typedef unsigned short u16;
typedef __bf16  bf16x8 __attribute__((ext_vector_type(8)));
typedef unsigned short u16x8 __attribute__((ext_vector_type(8)));
typedef unsigned short u16x4 __attribute__((ext_vector_type(4)));
typedef float   f32x4  __attribute__((ext_vector_type(4)));

#define LOG2E 1.44269504088896340736f

__device__ __forceinline__ u16 f2b(float f) {
  union { __bf16 h; u16 u; } c; c.h = (__bf16)f;   // native v_cvt (RNE) on gfx950
  return c.u;
}

// Granule (16B) XOR swizzle for [rows][64]-bf16 LDS tiles.
__device__ __forceinline__ int swz(int row) { return (row & 7) ^ ((row >> 3) & 7); }
__device__ __forceinline__ int sidx(int row, int k) {
  return row * 64 + ((((k >> 3) ^ swz(row)) & 7) << 3) + (k & 7);
}
__device__ __forceinline__ bf16x8 ld_frag(const u16* base, int row, int k) {
  return *(const bf16x8*)(base + sidx(row, k));
}

// async global->LDS, 16B/lane (attn staging only)
__device__ __forceinline__ void async16(const u16* g, u16* l) {
  __builtin_amdgcn_global_load_lds(
      (__attribute__((address_space(1))) unsigned int*)(uintptr_t)g,
      (__attribute__((address_space(3))) unsigned int*)(uintptr_t)l,
      16, 0, 0);
}

// permlane32_swap: lanes 32-63 of a <-> lanes 0-31 of b.
__device__ __forceinline__ void plswap32(unsigned int &a, unsigned int &b) {
  auto r = __builtin_amdgcn_permlane32_swap(a, b, false, false);
  a = r[0]; b = r[1];
}
// permlane16_swap: odd 16-rows of a <-> even 16-rows of b.
__device__ __forceinline__ void plswap16(unsigned int &a, unsigned int &b) {
#if __has_builtin(__builtin_amdgcn_permlane16_swap)
  auto r = __builtin_amdgcn_permlane16_swap(a, b, false, false);
  a = r[0]; b = r[1];
#else
  asm volatile("v_permlane16_swap_b32 %0, %1" : "+v"(a), "+v"(b));
#endif
}

// ---------------- fused LayerNorm + weight conversion (one dispatch) ----------------
__global__ __launch_bounds__(256) void prep_kernel(
    const float* __restrict__ hs, const float* __restrict__ gamma,
    const float* __restrict__ beta, u16* __restrict__ X,
    const float* __restrict__ w0, const float* __restrict__ w1,
    const float* __restrict__ w2, const float* __restrict__ w3,
    u16* __restrict__ Wd) {
  const int tid = threadIdx.x;
  if (blockIdx.x >= 4096) {
    // weight cvt: 4096 blocks, each 1024 elems
    const int idx4 = blockIdx.x - 4096;
    const int mat = idx4 >> 10;
    const float* src = (mat == 0) ? w0 : (mat == 1) ? w1 : (mat == 2) ? w2 : w3;
    const int idx = ((idx4 & 1023) * 256 + tid) * 4;
    f32x4 v = *(const f32x4*)(src + idx);
    u16x4 o;
#pragma unroll
    for (int j = 0; j < 4; ++j) o[j] = f2b(v[j]);
    *(u16x4*)(Wd + (size_t)mat * 1048576 + idx) = o;
    return;
  }
  __shared__ float red[8];
  const int row = blockIdx.x;
  f32x4 v = *(const f32x4*)(hs + (size_t)row * 1024 + tid * 4);
  float s = 0.f, s2 = 0.f;
#pragma unroll
  for (int j = 0; j < 4; ++j) { s += v[j]; s2 += v[j] * v[j]; }
#pragma unroll
  for (int o = 1; o < 64; o <<= 1) { s += __shfl_xor(s, o); s2 += __shfl_xor(s2, o); }
  const int wid = tid >> 6, lane = tid & 63;
  if (lane == 0) { red[wid] = s; red[4 + wid] = s2; }
  __syncthreads();
  s  = red[0] + red[1] + red[2] + red[3];
  s2 = red[4] + red[5] + red[6] + red[7];
  const float mean = s * (1.f / 1024.f);
  const float var  = fmaxf(s2 * (1.f / 1024.f) - mean * mean, 0.f);
  const float rstd = rsqrtf(var + 1e-12f);
  f32x4 g = *(const f32x4*)(gamma + tid * 4);
  f32x4 bb = *(const f32x4*)(beta + tid * 4);
  u16x4 outv;
#pragma unroll
  for (int j = 0; j < 4; ++j) outv[j] = f2b((v[j] - mean) * rstd * g[j] + bb[j]);
  *(u16x4*)(X + (size_t)row * 1024 + tid * 4) = outv;
}

// ---------------- 128x128 gemm_bt tile (K=1024), software-pipelined reg staging ------
// (R4 known-good; used by qkv: MODE 0 bf16 out, MODE 2 V-transpose out)
template <int MODE>
__device__ __forceinline__ void gemm_tile_128(
    const u16* __restrict__ A, const u16* __restrict__ Bt,
    const float* __restrict__ bias, const float* __restrict__ res,
    void* __restrict__ Cv, int ldc, int m0, int nG) {
  __shared__ __align__(16) u16 As[128 * 64];
  __shared__ __align__(16) u16 Bs[128 * 64];
  const int tid = threadIdx.x;
  const int wid = tid >> 6;
  const int lane = tid & 63;
  const int l15 = lane & 15, lq = lane >> 4;
  const int wm = (wid & 1) << 6, wn = (wid >> 1) << 6;
  const int srow = tid >> 3;   // 0..31
  const int sg = tid & 7;

  f32x4 acc[4][4] = {};
  u16x8 ar[4], br[4];

  // prefetch tile k0=0
#pragma unroll
  for (int i = 0; i < 4; ++i) {
    int row = (i << 5) + srow;
    ar[i] = *(const u16x8*)(A  + (size_t)row * 1024 + (sg << 3));
    br[i] = *(const u16x8*)(Bt + (size_t)row * 1024 + (sg << 3));
  }

  for (int k0 = 0; k0 < 1024; k0 += 64) {
    if (k0) __syncthreads();           // previous compute done with LDS
#pragma unroll
    for (int i = 0; i < 4; ++i) {
      int row = (i << 5) + srow;
      *(u16x8*)(As + sidx(row, sg << 3)) = ar[i];
      *(u16x8*)(Bs + sidx(row, sg << 3)) = br[i];
    }
    __syncthreads();                   // staged tile visible to all waves
    if (k0 + 64 < 1024) {              // prefetch next tile during compute
#pragma unroll
      for (int i = 0; i < 4; ++i) {
        int row = (i << 5) + srow;
        ar[i] = *(const u16x8*)(A  + (size_t)row * 1024 + k0 + 64 + (sg << 3));
        br[i] = *(const u16x8*)(Bt + (size_t)row * 1024 + k0 + 64 + (sg << 3));
      }
    }
#pragma unroll
    for (int kk = 0; kk < 2; ++kk) {
      bf16x8 af[4], bf[4];
#pragma unroll
      for (int mi = 0; mi < 4; ++mi) af[mi] = ld_frag(As, wm + (mi << 4) + l15, (kk << 5) + (lq << 3));
#pragma unroll
      for (int ni = 0; ni < 4; ++ni) bf[ni] = ld_frag(Bs, wn + (ni << 4) + l15, (kk << 5) + (lq << 3));
#pragma unroll
      for (int mi = 0; mi < 4; ++mi)
#pragma unroll
        for (int ni = 0; ni < 4; ++ni)
          acc[mi][ni] = __builtin_amdgcn_mfma_f32_16x16x32_bf16(af[mi], bf[ni], acc[mi][ni], 0, 0, 0);
    }
  }
  __syncthreads();   // last tile's LDS reads done before MODE 2 reuses As/Bs

  if (MODE == 2) {
    // V-transpose epilogue: per-wave 64x64 subtile -> LDS [n][m] -> coalesced VT rows.
    u16* Rg = (wid < 2 ? As : Bs) + ((wid & 1) << 12);
#pragma unroll
    for (int ni = 0; ni < 4; ++ni) {
      const float bv = bias[wn + (ni << 4) + l15];
#pragma unroll
      for (int mi = 0; mi < 4; ++mi) {
        u16x4 pk;
#pragma unroll
        for (int r = 0; r < 4; ++r) pk[r] = f2b(acc[mi][ni][r] + bv);
        *(u16x4*)(Rg + sidx((ni << 4) + l15, (mi << 4) + (lq << 2))) = pk;
      }
    }
    __asm__ volatile("" ::: "memory");   // same-wave DS in-order
    const int rrow = lane >> 3;
    const int rg8  = (lane & 7) << 3;
    const int mg0 = m0 + wm;
    const int bb = mg0 >> 11, ss0 = mg0 & 2047;
    const int hh = (nG + wn) >> 6;
    u16* vbase = (u16*)Cv + ((size_t)((bb << 4) + hh) * 64) * 2048 + ss0;
#pragma unroll
    for (int p = 0; p < 8; ++p) {
      const int nl = (p << 3) + rrow;
      bf16x8 rowv = ld_frag(Rg, nl, rg8);
      *(bf16x8*)(vbase + (size_t)nl * 2048 + rg8) = rowv;
    }
  } else {
#pragma unroll
    for (int ni = 0; ni < 4; ++ni) {
      const int n = wn + (ni << 4) + l15;
      const float bv = bias[n];
#pragma unroll
      for (int mi = 0; mi < 4; ++mi) {
#pragma unroll
        for (int r = 0; r < 4; ++r) {
          const int m = wm + (mi << 4) + (lq << 2) + r;
          float v = acc[mi][ni][r] + bv;
          if (MODE == 1) {
            v += res[(size_t)m * ldc + n];
            ((float*)Cv)[(size_t)m * ldc + n] = v;
          } else {
            ((u16*)Cv)[(size_t)m * ldc + n] = f2b(v);
          }
        }
      }
    }
  }
}

// ---------------- 128x64 gemm_bt tile for out: 2 blocks/CU restores overlap ----------
__device__ __forceinline__ void gemm_tile_out64(
    const u16* __restrict__ A, const u16* __restrict__ Bt,
    const float* __restrict__ bias, const float* __restrict__ res,
    float* __restrict__ Cv, int ldc) {
  __shared__ __align__(16) u16 As[128 * 64];
  __shared__ __align__(16) u16 Bs[64 * 64];
  const int tid = threadIdx.x;
  const int wid = tid >> 6;
  const int lane = tid & 63;
  const int l15 = lane & 15, lq = lane >> 4;
  const int wm = (wid & 1) << 6, wn = (wid >> 1) << 5;   // 2x64 m, 2x32 n
  const int srow = tid >> 3;   // 0..31
  const int sg = tid & 7;

  f32x4 acc[4][2] = {};
  u16x8 ar[4], br[2];

#pragma unroll
  for (int i = 0; i < 4; ++i)
    ar[i] = *(const u16x8*)(A + (size_t)(((i << 5) + srow)) * 1024 + (sg << 3));
#pragma unroll
  for (int i = 0; i < 2; ++i)
    br[i] = *(const u16x8*)(Bt + (size_t)(((i << 5) + srow)) * 1024 + (sg << 3));

  for (int k0 = 0; k0 < 1024; k0 += 64) {
    if (k0) __syncthreads();
#pragma unroll
    for (int i = 0; i < 4; ++i)
      *(u16x8*)(As + sidx((i << 5) + srow, sg << 3)) = ar[i];
#pragma unroll
    for (int i = 0; i < 2; ++i)
      *(u16x8*)(Bs + sidx((i << 5) + srow, sg << 3)) = br[i];
    __syncthreads();
    if (k0 + 64 < 1024) {
#pragma unroll
      for (int i = 0; i < 4; ++i)
        ar[i] = *(const u16x8*)(A + (size_t)(((i << 5) + srow)) * 1024 + k0 + 64 + (sg << 3));
#pragma unroll
      for (int i = 0; i < 2; ++i)
        br[i] = *(const u16x8*)(Bt + (size_t)(((i << 5) + srow)) * 1024 + k0 + 64 + (sg << 3));
    }
#pragma unroll
    for (int kk = 0; kk < 2; ++kk) {
      bf16x8 af[4], bf[2];
#pragma unroll
      for (int mi = 0; mi < 4; ++mi) af[mi] = ld_frag(As, wm + (mi << 4) + l15, (kk << 5) + (lq << 3));
#pragma unroll
      for (int ni = 0; ni < 2; ++ni) bf[ni] = ld_frag(Bs, wn + (ni << 4) + l15, (kk << 5) + (lq << 3));
#pragma unroll
      for (int mi = 0; mi < 4; ++mi)
#pragma unroll
        for (int ni = 0; ni < 2; ++ni)
          acc[mi][ni] = __builtin_amdgcn_mfma_f32_16x16x32_bf16(af[mi], bf[ni], acc[mi][ni], 0, 0, 0);
    }
  }

#pragma unroll
  for (int ni = 0; ni < 2; ++ni) {
    const int n = wn + (ni << 4) + l15;
    const float bv = bias[n];
#pragma unroll
    for (int mi = 0; mi < 4; ++mi) {
#pragma unroll
      for (int r = 0; r < 4; ++r) {
        const int m = wm + (mi << 4) + (lq << 2) + r;
        Cv[(size_t)m * ldc + n] = acc[mi][ni][r] + bv + res[(size_t)m * ldc + n];
      }
    }
  }
}

// fused QKV: X @ {wq,wk}^T -> QK[4096x2048]; X @ wv^T -> VT[(b,h,d)][s]
__global__ __launch_bounds__(256, 3) void qkv_kernel(
    const u16* __restrict__ X, const u16* __restrict__ W,
    const float* __restrict__ bq, const float* __restrict__ bk, const float* __restrict__ bv,
    u16* __restrict__ QK, u16* __restrict__ VT) {
  const int n0 = blockIdx.x << 7;
  const int m0 = blockIdx.y << 7;
  const int wsel = n0 >> 10;
  const int nloc = n0 & 1023;
  const u16* Bt = W + (size_t)wsel * 1048576 + (size_t)nloc * 1024;
  if (wsel < 2) {
    const float* bias = (wsel == 0 ? bq : bk) + nloc;
    gemm_tile_128<0>(X + (size_t)m0 * 1024, Bt, bias, nullptr,
                     QK + (size_t)m0 * 2048 + n0, 2048, 0, 0);
  } else {
    gemm_tile_128<2>(X + (size_t)m0 * 1024, Bt, bv + nloc, nullptr,
                     VT, 0, m0, nloc);
  }
}

// O-proj + bias + residual(fp32) -> OUT fp32; 128x64 tiles, 512 blocks (2/CU)
__global__ __launch_bounds__(256, 3) void out_kernel(
    const u16* __restrict__ CTX, const u16* __restrict__ wo,
    const float* __restrict__ bo, const float* __restrict__ res, float* __restrict__ OUT) {
  const int n0 = blockIdx.x << 6;
  const int m0 = blockIdx.y << 7;
  gemm_tile_out64(CTX + (size_t)m0 * 1024, wo + (size_t)n0 * 1024, bo + n0,
                  res + (size_t)m0 * 1024 + n0, OUT + (size_t)m0 * 1024 + n0, 1024);
}

// ---------------- flash attention: in-block k-split (waves 0-3: kt 0-15, waves 4-7:
// kt 16-31), R8 body per half (80 VGPR fits 128-cap at 4 waves/SIMD), LDS combine
// (R3-verified decomposition). 2 blocks/CU x 8 waves = 4 waves/SIMD. ----------------
__global__ __launch_bounds__(512, 4) void attn_kernel(
    const u16* __restrict__ QK, const u16* __restrict__ VT,
    const float* __restrict__ mask, u16* __restrict__ CTX) {
  __shared__ __align__(16) u16 Ksb[2][2][64 * 64];    // [half][dbuf] 8 KB each
  __shared__ __align__(16) u16 Vtsb[2][2][64 * 64];
  const int tid = threadIdx.x;
  const int wid = tid >> 6;            // 0..7
  const int half = wid >> 2;
  const int wid4 = wid & 3;
  const int lane = tid & 63;
  const int l15 = lane & 15, lq = lane >> 4;

  // XCD swizzle: each XCD gets 64 contiguous sw ids = 4 (h,b) groups x 16 q-tiles
  const int lid = blockIdx.x;
  const int sw = ((lid & 7) << 6) | (lid >> 3);
  const int qt = sw & 15;
  const int hz = sw >> 4;
  const int h = hz & 15;
  const int b = hz >> 4;

  const int qbase = (b << 11) + (qt << 7) + (wid4 << 5);
  const u16* Kbase  = QK + (size_t)(b << 11) * 2048 + 1024 + (h << 6);
  const u16* VTbase = VT + (size_t)(((b << 4) + h) << 6) * 2048;
  const int kt0 = half << 4;           // this half's first kt

  bf16x8 qf[2][2];
#pragma unroll
  for (int f = 0; f < 2; ++f)
#pragma unroll
    for (int kc = 0; kc < 2; ++kc)
      qf[f][kc] = *(const bf16x8*)(QK + (size_t)(qbase + (f << 4) + l15) * 2048 + (h << 6) + (kc << 5) + (lq << 3));

  bf16x8 onesf;
#pragma unroll
  for (int j = 0; j < 8; ++j) onesf[j] = (__bf16)1.0f;

  f32x4 cacc[2][4] = {};
  f32x4 lacc[2] = {};                  // P row-sum accumulator (ones-MFMA)

  const int sg = lane & 7;
  const int srow0 = (wid4 << 4) + (lane >> 3);
  const int srow1 = srow0 + 8;
  const int gk0 = ((sg ^ swz(srow0)) & 7) << 3;
  const int gk1 = ((sg ^ swz(srow1)) & 7) << 3;
  const int ld0 = ((wid4 << 1) + 0) << 9;
  const int ld1 = ((wid4 << 1) + 1) << 9;

  auto STAGE = [&](int lt) {           // lt = local tile index 0..15
    u16* kb = &Ksb[half][lt & 1][0];
    u16* vb = &Vtsb[half][lt & 1][0];
    const int nk = (kt0 + lt) << 6;
    async16(Kbase + (size_t)(nk + srow0) * 2048 + gk0, kb + ld0);
    async16(Kbase + (size_t)(nk + srow1) * 2048 + gk1, kb + ld1);
    async16(VTbase + (size_t)srow0 * 2048 + nk + gk0, vb + ld0);
    async16(VTbase + (size_t)srow1 * 2048 + nk + gk1, vb + ld1);
  };

  STAGE(0);

  for (int lt = 0; lt < 16; ++lt) {
    const u16* Ks  = &Ksb[half][lt & 1][0];
    const u16* Vts = &Vtsb[half][lt & 1][0];
    __syncthreads();                   // stage(lt) drained; prev compute done
    if (lt + 1 < 16) STAGE(lt + 1);

    // S^T = K Q^T  (sacc[f][ki]: lane (q=l15, k=16ki+4lq+r))
    f32x4 sacc[2][4] = {};
    __builtin_amdgcn_s_setprio(1);
#pragma unroll
    for (int kc = 0; kc < 2; ++kc) {
      bf16x8 kf[4];
#pragma unroll
      for (int ki = 0; ki < 4; ++ki) kf[ki] = ld_frag(Ks, (ki << 4) + l15, (kc << 5) + (lq << 3));
#pragma unroll
      for (int f = 0; f < 2; ++f)
#pragma unroll
        for (int ki = 0; ki < 4; ++ki)
          sacc[f][ki] = __builtin_amdgcn_mfma_f32_16x16x32_bf16(kf[ki], qf[f][kc], sacc[f][ki], 0, 0, 0);
    }
    __builtin_amdgcn_s_setprio(0);

    f32x4 mvl[4];
#pragma unroll
    for (int ki = 0; ki < 4; ++ki) {
      f32x4 mv = *(const f32x4*)(mask + (b << 11) + ((kt0 + lt) << 6) + (ki << 4) + (lq << 2));
#pragma unroll
      for (int r = 0; r < 4; ++r) mvl[ki][r] = mv[r] * LOG2E;
    }

    // softmax + in-register P pack (RNE cvt; row-sum via ones-MFMA below)
    unsigned int w0[2][4], w1[2][4];
#pragma unroll
    for (int f = 0; f < 2; ++f) {
#pragma unroll
      for (int ki = 0; ki < 4; ++ki) {
#pragma unroll
        for (int r = 0; r < 4; ++r)
          sacc[f][ki][r] = __builtin_amdgcn_exp2f(sacc[f][ki][r] * (0.125f * LOG2E) + mvl[ki][r]);
        unsigned int wa, wb;
        asm("v_cvt_pk_bf16_f32 %0, %1, %2" : "=v"(wa) : "v"(sacc[f][ki][0]), "v"(sacc[f][ki][1]));
        asm("v_cvt_pk_bf16_f32 %0, %1, %2" : "=v"(wb) : "v"(sacc[f][ki][2]), "v"(sacc[f][ki][3]));
        w0[f][ki] = wa; w1[f][ki] = wb;
      }
    }

    // ctx^T += VT P^T ; l += ones P^T
#pragma unroll
    for (int kc = 0; kc < 2; ++kc) {
      bf16x8 pf[2];
#pragma unroll
      for (int f = 0; f < 2; ++f) {
        unsigned int a0 = w0[f][(kc << 1) + 0], a1 = w1[f][(kc << 1) + 0];
        unsigned int b0 = w0[f][(kc << 1) + 1], b1 = w1[f][(kc << 1) + 1];
        plswap32(a0, b0); plswap32(a1, b1);
        plswap16(a0, b0); plswap16(a1, b1);
        union { unsigned int u[4]; bf16x8 v; } pc;
        pc.u[0] = a0; pc.u[1] = a1; pc.u[2] = b0; pc.u[3] = b1;
        pf[f] = pc.v;
      }
      __builtin_amdgcn_s_setprio(1);
#pragma unroll
      for (int dm = 0; dm < 4; ++dm) {
        bf16x8 vf = ld_frag(Vts, (dm << 4) + l15, (kc << 5) + (lq << 3));
#pragma unroll
        for (int f = 0; f < 2; ++f)
          cacc[f][dm] = __builtin_amdgcn_mfma_f32_16x16x32_bf16(vf, pf[f], cacc[f][dm], 0, 0, 0);
      }
#pragma unroll
      for (int f = 0; f < 2; ++f)
        lacc[f] = __builtin_amdgcn_mfma_f32_16x16x32_bf16(onesf, pf[f], lacc[f], 0, 0, 0);
      __builtin_amdgcn_s_setprio(0);
    }
  }

  // ---- combine the two k-halves through LDS (reuse K/V buffers), then normalize
  float* CombC = (float*)&Ksb[0][0][0];   // 4 waves x 64 lanes x 32 f32 = 32 KB
  float* CombL = (float*)&Vtsb[0][0][0];  // 4 waves x 64 lanes x 2 f32
  __syncthreads();                        // all waves done reading K/V LDS
  if (half == 1) {
    float* dst = CombC + (wid4 << 11) + (lane << 5);
#pragma unroll
    for (int j = 0; j < 8; ++j)
      *(f32x4*)(dst + (((j ^ swz(lane)) & 7) << 2)) = cacc[j >> 2][j & 3];
    CombL[(wid4 << 7) + (lane << 1) + 0] = lacc[0][0];
    CombL[(wid4 << 7) + (lane << 1) + 1] = lacc[1][0];
  }
  __syncthreads();
  if (half == 0) {
    float* src = CombC + (wid4 << 11) + (lane << 5);
#pragma unroll
    for (int j = 0; j < 8; ++j) {
      f32x4 t = *(const f32x4*)(src + (((j ^ swz(lane)) & 7) << 2));
      cacc[j >> 2][j & 3] += t;
    }
    const float l0 = lacc[0][0] + CombL[(wid4 << 7) + (lane << 1) + 0];
    const float l1 = lacc[1][0] + CombL[(wid4 << 7) + (lane << 1) + 1];
#pragma unroll
    for (int f = 0; f < 2; ++f) {
      const float inv = 1.0f / (f == 0 ? l0 : l1);
      u16* Crow = CTX + (size_t)(qbase + (f << 4) + l15) * 1024 + (h << 6);
#pragma unroll
      for (int dm = 0; dm < 4; ++dm) {
        u16x4 o;
#pragma unroll
        for (int r = 0; r < 4; ++r) o[r] = f2b(cacc[f][dm][r] * inv);
        *(u16x4*)(Crow + (dm << 4) + (lq << 2)) = o;
      }
    }
  }
}

extern "C" void kernel_launch(void* const* d_in, const int* in_sizes, int n_in,
                              void* d_out, int out_size, void* d_ws, size_t ws_size,
                              hipStream_t stream) {
  const float* hs   = (const float*)d_in[0];
  const float* mask = (const float*)d_in[1];
  const float* wq   = (const float*)d_in[2];
  const float* bq   = (const float*)d_in[3];
  const float* wk   = (const float*)d_in[4];
  const float* bk   = (const float*)d_in[5];
  const float* wv   = (const float*)d_in[6];
  const float* bv   = (const float*)d_in[7];
  const float* wo   = (const float*)d_in[8];
  const float* bo   = (const float*)d_in[9];
  const float* lg   = (const float*)d_in[10];
  const float* lb   = (const float*)d_in[11];

  u16* X   = (u16*)d_ws;                       // 4096x1024 bf16   (8 MiB)
  u16* QK  = X + (size_t)4096 * 1024;          // 4096x2048 bf16   (16 MiB)
  u16* CTX = QK + (size_t)4096 * 2048;         // 4096x1024 bf16   (8 MiB)
  u16* W   = CTX + (size_t)4096 * 1024;        // wq|wk|wv|wo bf16 (8 MiB)
  u16* VT  = W + (size_t)4 * 1048576;          // [b,h,d][s] bf16  (8 MiB)
  float* OUT = (float*)d_out;

  prep_kernel<<<8192, 256, 0, stream>>>(hs, lg, lb, X, wq, wk, wv, wo, W);
  qkv_kernel<<<dim3(24, 32), 256, 0, stream>>>(X, W, bq, bk, bv, QK, VT);
  attn_kernel<<<dim3(512), 512, 0, stream>>>(QK, VT, mask, CTX);
  out_kernel<<<dim3(16, 32), 256, 0, stream>>>(CTX, W + (size_t)3 * 1048576, bo, hs, OUT);
}

// Round 13
// 196.388 us; speedup vs baseline: 1.1427x; 1.1427x over previous
//
#include <hip/hip_runtime.h>
#include <cstdint>

typedef unsigned short u16;
typedef __bf16  bf16x8 __attribute__((ext_vector_type(8)));
typedef unsigned short u16x8 __attribute__((ext_vector_type(8)));
typedef unsigned short u16x4 __attribute__((ext_vector_type(4)));
typedef float   f32x4  __attribute__((ext_vector_type(4)));

#define LOG2E 1.44269504088896340736f

__device__ __forceinline__ u16 f2b(float f) {
  union { __bf16 h; u16 u; } c; c.h = (__bf16)f;   // native v_cvt (RNE) on gfx950
  return c.u;
}

// Granule (16B) XOR swizzle for [rows][64]-bf16 LDS tiles.
__device__ __forceinline__ int swz(int row) { return (row & 7) ^ ((row >> 3) & 7); }
__device__ __forceinline__ int sidx(int row, int k) {
  return row * 64 + ((((k >> 3) ^ swz(row)) & 7) << 3) + (k & 7);
}
__device__ __forceinline__ bf16x8 ld_frag(const u16* base, int row, int k) {
  return *(const bf16x8*)(base + sidx(row, k));
}

// async global->LDS, 16B/lane (attn staging only)
__device__ __forceinline__ void async16(const u16* g, u16* l) {
  __builtin_amdgcn_global_load_lds(
      (__attribute__((address_space(1))) unsigned int*)(uintptr_t)g,
      (__attribute__((address_space(3))) unsigned int*)(uintptr_t)l,
      16, 0, 0);
}

// permlane32_swap: lanes 32-63 of a <-> lanes 0-31 of b.
__device__ __forceinline__ void plswap32(unsigned int &a, unsigned int &b) {
  auto r = __builtin_amdgcn_permlane32_swap(a, b, false, false);
  a = r[0]; b = r[1];
}
// permlane16_swap: odd 16-rows of a <-> even 16-rows of b.
__device__ __forceinline__ void plswap16(unsigned int &a, unsigned int &b) {
#if __has_builtin(__builtin_amdgcn_permlane16_swap)
  auto r = __builtin_amdgcn_permlane16_swap(a, b, false, false);
  a = r[0]; b = r[1];
#else
  asm volatile("v_permlane16_swap_b32 %0, %1" : "+v"(a), "+v"(b));
#endif
}

// ---------------- fused LayerNorm + weight conversion (one dispatch) ----------------
__global__ __launch_bounds__(256) void prep_kernel(
    const float* __restrict__ hs, const float* __restrict__ gamma,
    const float* __restrict__ beta, u16* __restrict__ X,
    const float* __restrict__ w0, const float* __restrict__ w1,
    const float* __restrict__ w2, const float* __restrict__ w3,
    u16* __restrict__ Wd) {
  const int tid = threadIdx.x;
  if (blockIdx.x >= 4096) {
    // weight cvt: 4096 blocks, each 1024 elems
    const int idx4 = blockIdx.x - 4096;
    const int mat = idx4 >> 10;
    const float* src = (mat == 0) ? w0 : (mat == 1) ? w1 : (mat == 2) ? w2 : w3;
    const int idx = ((idx4 & 1023) * 256 + tid) * 4;
    f32x4 v = *(const f32x4*)(src + idx);
    u16x4 o;
#pragma unroll
    for (int j = 0; j < 4; ++j) o[j] = f2b(v[j]);
    *(u16x4*)(Wd + (size_t)mat * 1048576 + idx) = o;
    return;
  }
  __shared__ float red[8];
  const int row = blockIdx.x;
  f32x4 v = *(const f32x4*)(hs + (size_t)row * 1024 + tid * 4);
  float s = 0.f, s2 = 0.f;
#pragma unroll
  for (int j = 0; j < 4; ++j) { s += v[j]; s2 += v[j] * v[j]; }
#pragma unroll
  for (int o = 1; o < 64; o <<= 1) { s += __shfl_xor(s, o); s2 += __shfl_xor(s2, o); }
  const int wid = tid >> 6, lane = tid & 63;
  if (lane == 0) { red[wid] = s; red[4 + wid] = s2; }
  __syncthreads();
  s  = red[0] + red[1] + red[2] + red[3];
  s2 = red[4] + red[5] + red[6] + red[7];
  const float mean = s * (1.f / 1024.f);
  const float var  = fmaxf(s2 * (1.f / 1024.f) - mean * mean, 0.f);
  const float rstd = rsqrtf(var + 1e-12f);
  f32x4 g = *(const f32x4*)(gamma + tid * 4);
  f32x4 bb = *(const f32x4*)(beta + tid * 4);
  u16x4 outv;
#pragma unroll
  for (int j = 0; j < 4; ++j) outv[j] = f2b((v[j] - mean) * rstd * g[j] + bb[j]);
  *(u16x4*)(X + (size_t)row * 1024 + tid * 4) = outv;
}

// ---------------- 128x128 gemm_bt tile (K=1024), software-pipelined reg staging ------
// (R4 known-good; used by qkv: MODE 0 bf16 out, MODE 2 V-transpose out)
template <int MODE>
__device__ __forceinline__ void gemm_tile_128(
    const u16* __restrict__ A, const u16* __restrict__ Bt,
    const float* __restrict__ bias, const float* __restrict__ res,
    void* __restrict__ Cv, int ldc, int m0, int nG) {
  __shared__ __align__(16) u16 As[128 * 64];
  __shared__ __align__(16) u16 Bs[128 * 64];
  const int tid = threadIdx.x;
  const int wid = tid >> 6;
  const int lane = tid & 63;
  const int l15 = lane & 15, lq = lane >> 4;
  const int wm = (wid & 1) << 6, wn = (wid >> 1) << 6;
  const int srow = tid >> 3;   // 0..31
  const int sg = tid & 7;

  f32x4 acc[4][4] = {};
  u16x8 ar[4], br[4];

  // prefetch tile k0=0
#pragma unroll
  for (int i = 0; i < 4; ++i) {
    int row = (i << 5) + srow;
    ar[i] = *(const u16x8*)(A  + (size_t)row * 1024 + (sg << 3));
    br[i] = *(const u16x8*)(Bt + (size_t)row * 1024 + (sg << 3));
  }

  for (int k0 = 0; k0 < 1024; k0 += 64) {
    if (k0) __syncthreads();           // previous compute done with LDS
#pragma unroll
    for (int i = 0; i < 4; ++i) {
      int row = (i << 5) + srow;
      *(u16x8*)(As + sidx(row, sg << 3)) = ar[i];
      *(u16x8*)(Bs + sidx(row, sg << 3)) = br[i];
    }
    __syncthreads();                   // staged tile visible to all waves
    if (k0 + 64 < 1024) {              // prefetch next tile during compute
#pragma unroll
      for (int i = 0; i < 4; ++i) {
        int row = (i << 5) + srow;
        ar[i] = *(const u16x8*)(A  + (size_t)row * 1024 + k0 + 64 + (sg << 3));
        br[i] = *(const u16x8*)(Bt + (size_t)row * 1024 + k0 + 64 + (sg << 3));
      }
    }
#pragma unroll
    for (int kk = 0; kk < 2; ++kk) {
      bf16x8 af[4], bf[4];
#pragma unroll
      for (int mi = 0; mi < 4; ++mi) af[mi] = ld_frag(As, wm + (mi << 4) + l15, (kk << 5) + (lq << 3));
#pragma unroll
      for (int ni = 0; ni < 4; ++ni) bf[ni] = ld_frag(Bs, wn + (ni << 4) + l15, (kk << 5) + (lq << 3));
#pragma unroll
      for (int mi = 0; mi < 4; ++mi)
#pragma unroll
        for (int ni = 0; ni < 4; ++ni)
          acc[mi][ni] = __builtin_amdgcn_mfma_f32_16x16x32_bf16(af[mi], bf[ni], acc[mi][ni], 0, 0, 0);
    }
  }
  __syncthreads();   // last tile's LDS reads done before MODE 2 reuses As/Bs

  if (MODE == 2) {
    // V-transpose epilogue: per-wave 64x64 subtile -> LDS [n][m] -> coalesced VT rows.
    u16* Rg = (wid < 2 ? As : Bs) + ((wid & 1) << 12);
#pragma unroll
    for (int ni = 0; ni < 4; ++ni) {
      const float bv = bias[wn + (ni << 4) + l15];
#pragma unroll
      for (int mi = 0; mi < 4; ++mi) {
        u16x4 pk;
#pragma unroll
        for (int r = 0; r < 4; ++r) pk[r] = f2b(acc[mi][ni][r] + bv);
        *(u16x4*)(Rg + sidx((ni << 4) + l15, (mi << 4) + (lq << 2))) = pk;
      }
    }
    __asm__ volatile("" ::: "memory");   // same-wave DS in-order
    const int rrow = lane >> 3;
    const int rg8  = (lane & 7) << 3;
    const int mg0 = m0 + wm;
    const int bb = mg0 >> 11, ss0 = mg0 & 2047;
    const int hh = (nG + wn) >> 6;
    u16* vbase = (u16*)Cv + ((size_t)((bb << 4) + hh) * 64) * 2048 + ss0;
#pragma unroll
    for (int p = 0; p < 8; ++p) {
      const int nl = (p << 3) + rrow;
      bf16x8 rowv = ld_frag(Rg, nl, rg8);
      *(bf16x8*)(vbase + (size_t)nl * 2048 + rg8) = rowv;
    }
  } else {
#pragma unroll
    for (int ni = 0; ni < 4; ++ni) {
      const int n = wn + (ni << 4) + l15;
      const float bv = bias[n];
#pragma unroll
      for (int mi = 0; mi < 4; ++mi) {
#pragma unroll
        for (int r = 0; r < 4; ++r) {
          const int m = wm + (mi << 4) + (lq << 2) + r;
          float v = acc[mi][ni][r] + bv;
          if (MODE == 1) {
            v += res[(size_t)m * ldc + n];
            ((float*)Cv)[(size_t)m * ldc + n] = v;
          } else {
            ((u16*)Cv)[(size_t)m * ldc + n] = f2b(v);
          }
        }
      }
    }
  }
}

// ---------------- 128x64 gemm_bt tile for out: 2 blocks/CU restores overlap ----------
__device__ __forceinline__ void gemm_tile_out64(
    const u16* __restrict__ A, const u16* __restrict__ Bt,
    const float* __restrict__ bias, const float* __restrict__ res,
    float* __restrict__ Cv, int ldc) {
  __shared__ __align__(16) u16 As[128 * 64];
  __shared__ __align__(16) u16 Bs[64 * 64];
  const int tid = threadIdx.x;
  const int wid = tid >> 6;
  const int lane = tid & 63;
  const int l15 = lane & 15, lq = lane >> 4;
  const int wm = (wid & 1) << 6, wn = (wid >> 1) << 5;   // 2x64 m, 2x32 n
  const int srow = tid >> 3;   // 0..31
  const int sg = tid & 7;

  f32x4 acc[4][2] = {};
  u16x8 ar[4], br[2];

#pragma unroll
  for (int i = 0; i < 4; ++i)
    ar[i] = *(const u16x8*)(A + (size_t)(((i << 5) + srow)) * 1024 + (sg << 3));
#pragma unroll
  for (int i = 0; i < 2; ++i)
    br[i] = *(const u16x8*)(Bt + (size_t)(((i << 5) + srow)) * 1024 + (sg << 3));

  for (int k0 = 0; k0 < 1024; k0 += 64) {
    if (k0) __syncthreads();
#pragma unroll
    for (int i = 0; i < 4; ++i)
      *(u16x8*)(As + sidx((i << 5) + srow, sg << 3)) = ar[i];
#pragma unroll
    for (int i = 0; i < 2; ++i)
      *(u16x8*)(Bs + sidx((i << 5) + srow, sg << 3)) = br[i];
    __syncthreads();
    if (k0 + 64 < 1024) {
#pragma unroll
      for (int i = 0; i < 4; ++i)
        ar[i] = *(const u16x8*)(A + (size_t)(((i << 5) + srow)) * 1024 + k0 + 64 + (sg << 3));
#pragma unroll
      for (int i = 0; i < 2; ++i)
        br[i] = *(const u16x8*)(Bt + (size_t)(((i << 5) + srow)) * 1024 + k0 + 64 + (sg << 3));
    }
#pragma unroll
    for (int kk = 0; kk < 2; ++kk) {
      bf16x8 af[4], bf[2];
#pragma unroll
      for (int mi = 0; mi < 4; ++mi) af[mi] = ld_frag(As, wm + (mi << 4) + l15, (kk << 5) + (lq << 3));
#pragma unroll
      for (int ni = 0; ni < 2; ++ni) bf[ni] = ld_frag(Bs, wn + (ni << 4) + l15, (kk << 5) + (lq << 3));
#pragma unroll
      for (int mi = 0; mi < 4; ++mi)
#pragma unroll
        for (int ni = 0; ni < 2; ++ni)
          acc[mi][ni] = __builtin_amdgcn_mfma_f32_16x16x32_bf16(af[mi], bf[ni], acc[mi][ni], 0, 0, 0);
    }
  }

#pragma unroll
  for (int ni = 0; ni < 2; ++ni) {
    const int n = wn + (ni << 4) + l15;
    const float bv = bias[n];
#pragma unroll
    for (int mi = 0; mi < 4; ++mi) {
#pragma unroll
      for (int r = 0; r < 4; ++r) {
        const int m = wm + (mi << 4) + (lq << 2) + r;
        Cv[(size_t)m * ldc + n] = acc[mi][ni][r] + bv + res[(size_t)m * ldc + n];
      }
    }
  }
}

// fused QKV: X @ {wq,wk}^T -> QK[4096x2048]; X @ wv^T -> VT[(b,h,d)][s]
__global__ __launch_bounds__(256, 3) void qkv_kernel(
    const u16* __restrict__ X, const u16* __restrict__ W,
    const float* __restrict__ bq, const float* __restrict__ bk, const float* __restrict__ bv,
    u16* __restrict__ QK, u16* __restrict__ VT) {
  const int n0 = blockIdx.x << 7;
  const int m0 = blockIdx.y << 7;
  const int wsel = n0 >> 10;
  const int nloc = n0 & 1023;
  const u16* Bt = W + (size_t)wsel * 1048576 + (size_t)nloc * 1024;
  if (wsel < 2) {
    const float* bias = (wsel == 0 ? bq : bk) + nloc;
    gemm_tile_128<0>(X + (size_t)m0 * 1024, Bt, bias, nullptr,
                     QK + (size_t)m0 * 2048 + n0, 2048, 0, 0);
  } else {
    gemm_tile_128<2>(X + (size_t)m0 * 1024, Bt, bv + nloc, nullptr,
                     VT, 0, m0, nloc);
  }
}

// O-proj + bias + residual(fp32) -> OUT fp32; 128x64 tiles, 512 blocks (2/CU)
__global__ __launch_bounds__(256, 3) void out_kernel(
    const u16* __restrict__ CTX, const u16* __restrict__ wo,
    const float* __restrict__ bo, const float* __restrict__ res, float* __restrict__ OUT) {
  const int n0 = blockIdx.x << 6;
  const int m0 = blockIdx.y << 7;
  gemm_tile_out64(CTX + (size_t)m0 * 1024, wo + (size_t)n0 * 1024, bo + n0,
                  res + (size_t)m0 * 1024 + n0, OUT + (size_t)m0 * 1024 + n0, 1024);
}

// ---------------- attn helpers (R11 per-tile semantics, unchanged numerics) ----------
__device__ __forceinline__ void qk_tile(const u16* Ks, const bf16x8 (&qf)[2][2],
                                        f32x4 (&sacc)[2][4], int l15, int lq) {
  f32x4 z = {};
#pragma unroll
  for (int f = 0; f < 2; ++f)
#pragma unroll
    for (int ki = 0; ki < 4; ++ki) sacc[f][ki] = z;
  __builtin_amdgcn_s_setprio(1);
#pragma unroll
  for (int kc = 0; kc < 2; ++kc) {
    bf16x8 kf[4];
#pragma unroll
    for (int ki = 0; ki < 4; ++ki) kf[ki] = ld_frag(Ks, (ki << 4) + l15, (kc << 5) + (lq << 3));
#pragma unroll
    for (int f = 0; f < 2; ++f)
#pragma unroll
      for (int ki = 0; ki < 4; ++ki)
        sacc[f][ki] = __builtin_amdgcn_mfma_f32_16x16x32_bf16(kf[ki], qf[f][kc], sacc[f][ki], 0, 0, 0);
  }
  __builtin_amdgcn_s_setprio(0);
}

__device__ __forceinline__ void mask_load(const float* mp, f32x4 (&mvl)[4]) {
#pragma unroll
  for (int ki = 0; ki < 4; ++ki) {
    f32x4 mv = *(const f32x4*)(mp + (ki << 4));
#pragma unroll
    for (int r = 0; r < 4; ++r) mvl[ki][r] = mv[r] * LOG2E;
  }
}

// preload all 8 V-frags of a tile into registers (indices compile-time -> no scratch)
__device__ __forceinline__ void vf_load(const u16* Vts, bf16x8 (&vf)[2][4], int l15, int lq) {
#pragma unroll
  for (int kc = 0; kc < 2; ++kc)
#pragma unroll
    for (int dm = 0; dm < 4; ++dm)
      vf[kc][dm] = ld_frag(Vts, (dm << 4) + l15, (kc << 5) + (lq << 3));
}

__device__ __forceinline__ void softmax_pack(f32x4 (&sacc)[2][4], const f32x4 (&mvl)[4],
                                             unsigned int (&w0)[2][4], unsigned int (&w1)[2][4]) {
#pragma unroll
  for (int f = 0; f < 2; ++f) {
#pragma unroll
    for (int ki = 0; ki < 4; ++ki) {
#pragma unroll
      for (int r = 0; r < 4; ++r)
        sacc[f][ki][r] = __builtin_amdgcn_exp2f(sacc[f][ki][r] * (0.125f * LOG2E) + mvl[ki][r]);
      unsigned int wa, wb;
      asm("v_cvt_pk_bf16_f32 %0, %1, %2" : "=v"(wa) : "v"(sacc[f][ki][0]), "v"(sacc[f][ki][1]));
      asm("v_cvt_pk_bf16_f32 %0, %1, %2" : "=v"(wb) : "v"(sacc[f][ki][2]), "v"(sacc[f][ki][3]));
      w0[f][ki] = wa; w1[f][ki] = wb;
    }
  }
}

// PV from preloaded V-frags: pure register path (permlane + MFMA), no LDS on chain
__device__ __forceinline__ void pv_tile_reg(const bf16x8 (&vf)[2][4], unsigned int (&w0)[2][4],
                                            unsigned int (&w1)[2][4], f32x4 (&cacc)[2][4],
                                            f32x4 (&lacc)[2], bf16x8 onesf) {
#pragma unroll
  for (int kc = 0; kc < 2; ++kc) {
    bf16x8 pf[2];
#pragma unroll
    for (int f = 0; f < 2; ++f) {
      unsigned int a0 = w0[f][(kc << 1) + 0], a1 = w1[f][(kc << 1) + 0];
      unsigned int b0 = w0[f][(kc << 1) + 1], b1 = w1[f][(kc << 1) + 1];
      plswap32(a0, b0); plswap32(a1, b1);
      plswap16(a0, b0); plswap16(a1, b1);
      union { unsigned int u[4]; bf16x8 v; } pc;
      pc.u[0] = a0; pc.u[1] = a1; pc.u[2] = b0; pc.u[3] = b1;
      pf[f] = pc.v;
    }
    __builtin_amdgcn_s_setprio(1);
#pragma unroll
    for (int dm = 0; dm < 4; ++dm)
#pragma unroll
      for (int f = 0; f < 2; ++f)
        cacc[f][dm] = __builtin_amdgcn_mfma_f32_16x16x32_bf16(vf[kc][dm], pf[f], cacc[f][dm], 0, 0, 0);
#pragma unroll
    for (int f = 0; f < 2; ++f)
      lacc[f] = __builtin_amdgcn_mfma_f32_16x16x32_bf16(onesf, pf[f], lacc[f], 0, 0, 0);
    __builtin_amdgcn_s_setprio(0);
  }
}

// ---------------- flash attention: T15 pipeline + V-frag register hoist (R11 exact).
// Body(t): STAGE(t+3) | mask(t+1) | vf_load(V(t)) | softmax(t) | QK(t+1) | PV_reg(t).
__global__ __launch_bounds__(256, 2) void attn_kernel(
    const u16* __restrict__ QK, const u16* __restrict__ VT,
    const float* __restrict__ mask, u16* __restrict__ CTX) {
  __shared__ __align__(16) u16 Ksb[4][64 * 64];
  __shared__ __align__(16) u16 Vtsb[4][64 * 64];
  const int tid = threadIdx.x;
  const int wid = tid >> 6;            // 0..3
  const int lane = tid & 63;
  const int l15 = lane & 15, lq = lane >> 4;

  // XCD swizzle: each XCD gets 64 contiguous sw ids = 4 (h,b) groups x 16 q-tiles
  const int lid = blockIdx.x;
  const int sw = ((lid & 7) << 6) | (lid >> 3);
  const int qt = sw & 15;
  const int hz = sw >> 4;
  const int h = hz & 15;
  const int b = hz >> 4;

  const int qbase = (b << 11) + (qt << 7) + (wid << 5);
  const u16* Kbase  = QK + (size_t)(b << 11) * 2048 + 1024 + (h << 6);
  const u16* VTbase = VT + (size_t)(((b << 4) + h) << 6) * 2048;
  const float* Mbase = mask + (b << 11) + (lq << 2);

  bf16x8 qf[2][2];
#pragma unroll
  for (int f = 0; f < 2; ++f)
#pragma unroll
    for (int kc = 0; kc < 2; ++kc)
      qf[f][kc] = *(const bf16x8*)(QK + (size_t)(qbase + (f << 4) + l15) * 2048 + (h << 6) + (kc << 5) + (lq << 3));

  bf16x8 onesf;
#pragma unroll
  for (int j = 0; j < 8; ++j) onesf[j] = (__bf16)1.0f;

  f32x4 cacc[2][4] = {};
  f32x4 lacc[2] = {};                  // P row-sum accumulator (ones-MFMA)

  const int sg = lane & 7;
  const int srow0 = (wid << 4) + (lane >> 3);
  const int srow1 = srow0 + 8;
  const int gk0 = ((sg ^ swz(srow0)) & 7) << 3;
  const int gk1 = ((sg ^ swz(srow1)) & 7) << 3;
  const int ld0 = ((wid << 1) + 0) << 9;
  const int ld1 = ((wid << 1) + 1) << 9;

  auto STAGE = [&](int t) {
    u16* kb = &Ksb[t & 3][0];
    u16* vb = &Vtsb[t & 3][0];
    const int nk = t << 6;
    async16(Kbase + (size_t)(nk + srow0) * 2048 + gk0, kb + ld0);
    async16(Kbase + (size_t)(nk + srow1) * 2048 + gk1, kb + ld1);
    async16(VTbase + (size_t)srow0 * 2048 + nk + gk0, vb + ld0);
    async16(VTbase + (size_t)srow1 * 2048 + nk + gk1, vb + ld1);
  };

  STAGE(0); STAGE(1); STAGE(2);
  __syncthreads();                     // tiles 0..2 staged & visible

  f32x4 saccA[2][4], saccB[2][4];
  f32x4 mvlA[4], mvlB[4];
  qk_tile(&Ksb[0][0], qf, saccA, l15, lq);
  mask_load(Mbase, mvlA);              // mask(0)

  for (int i = 0; i < 16; ++i) {
    const int e = i << 1;              // even tile: consume A, produce B
    if (e + 3 < 32) STAGE(e + 3);
    mask_load(Mbase + ((e + 1) << 6), mvlB);
    {
      bf16x8 vfe[2][4];
      vf_load(&Vtsb[e & 3][0], vfe, l15, lq);   // V reads drain under softmax
      unsigned int w0[2][4], w1[2][4];
      softmax_pack(saccA, mvlA, w0, w1);
      qk_tile(&Ksb[(e + 1) & 3][0], qf, saccB, l15, lq);
      pv_tile_reg(vfe, w0, w1, cacc, lacc, onesf);
    }
    __syncthreads();                   // all waves done PV(e); stage(e+3) drained

    const int o = e + 1;               // odd tile: consume B, produce A
    if (o + 3 < 32) STAGE(o + 3);
    if (o < 31) mask_load(Mbase + ((o + 1) << 6), mvlA);
    {
      bf16x8 vfo[2][4];
      vf_load(&Vtsb[o & 3][0], vfo, l15, lq);
      unsigned int w0[2][4], w1[2][4];
      softmax_pack(saccB, mvlB, w0, w1);
      if (o < 31) qk_tile(&Ksb[(o + 1) & 3][0], qf, saccA, l15, lq);
      pv_tile_reg(vfo, w0, w1, cacc, lacc, onesf);
    }
    __syncthreads();
  }

#pragma unroll
  for (int f = 0; f < 2; ++f) {
    // every C row of lacc holds the same full row-sum over k; no cross-lane reduce
    const float inv = 1.0f / lacc[f][0];
    u16* Crow = CTX + (size_t)(qbase + (f << 4) + l15) * 1024 + (h << 6);
#pragma unroll
    for (int dm = 0; dm < 4; ++dm) {
      u16x4 o;
#pragma unroll
      for (int r = 0; r < 4; ++r) o[r] = f2b(cacc[f][dm][r] * inv);
      *(u16x4*)(Crow + (dm << 4) + (lq << 2)) = o;
    }
  }
}

extern "C" void kernel_launch(void* const* d_in, const int* in_sizes, int n_in,
                              void* d_out, int out_size, void* d_ws, size_t ws_size,
                              hipStream_t stream) {
  const float* hs   = (const float*)d_in[0];
  const float* mask = (const float*)d_in[1];
  const float* wq   = (const float*)d_in[2];
  const float* bq   = (const float*)d_in[3];
  const float* wk   = (const float*)d_in[4];
  const float* bk   = (const float*)d_in[5];
  const float* wv   = (const float*)d_in[6];
  const float* bv   = (const float*)d_in[7];
  const float* wo   = (const float*)d_in[8];
  const float* bo   = (const float*)d_in[9];
  const float* lg   = (const float*)d_in[10];
  const float* lb   = (const float*)d_in[11];

  u16* X   = (u16*)d_ws;                       // 4096x1024 bf16   (8 MiB)
  u16* QK  = X + (size_t)4096 * 1024;          // 4096x2048 bf16   (16 MiB)
  u16* CTX = QK + (size_t)4096 * 2048;         // 4096x1024 bf16   (8 MiB)
  u16* W   = CTX + (size_t)4096 * 1024;        // wq|wk|wv|wo bf16 (8 MiB)
  u16* VT  = W + (size_t)4 * 1048576;          // [b,h,d][s] bf16  (8 MiB)
  float* OUT = (float*)d_out;

  prep_kernel<<<8192, 256, 0, stream>>>(hs, lg, lb, X, wq, wk, wv, wo, W);
  qkv_kernel<<<dim3(24, 32), 256, 0, stream>>>(X, W, bq, bk, bv, QK, VT);
  attn_kernel<<<dim3(512), 256, 0, stream>>>(QK, VT, mask, CTX);
  out_kernel<<<dim3(16, 32), 256, 0, stream>>>(CTX, W + (size_t)3 * 1048576, bo, hs, OUT);
}